// Round 7
// baseline (2039.799 us; speedup 1.0000x reference)
//
#include <hip/hip_runtime.h>
#include <math.h>

#define NPIX 1600
#define NIMG 40
#define SW   40              // bf16 plane row stride: 80 B = 5*16 B -> conflict-free b128
#define PSZ  (48 * SW)       // shorts per plane (48 rows x 40 cols)

// mix_mfma LDS strides (complex units)
#define RST 322              // raw F slab: per-b stride = 40*8 + 2 pad (2576 B, 16-mult)
#define OST 482              // out slab: per-b stride = 48*10 + 2 pad (3856 B, 16-mult)

typedef __bf16 bf16x8 __attribute__((ext_vector_type(8)));
typedef float  f32x4  __attribute__((ext_vector_type(4)));
typedef unsigned int u32x4v __attribute__((ext_vector_type(4)));
#define MFMA __builtin_amdgcn_mfma_f32_16x16x32_bf16

__device__ __forceinline__ unsigned short bits16(__bf16 x) {
    return __builtin_bit_cast(unsigned short, x);
}

// exact bf16x8 negation (sign-bit flip on packed pairs)
__device__ __forceinline__ bf16x8 bneg(bf16x8 x) {
    u32x4v u = __builtin_bit_cast(u32x4v, x);
    u = u ^ (u32x4v){0x80008000u, 0x80008000u, 0x80008000u, 0x80008000u};
    return __builtin_bit_cast(bf16x8, u);
}

__device__ __forceinline__ void cfma(float2& acc, float ax, float ay, float bx, float by) {
    acc.x = fmaf(ax, bx, fmaf(-ay, by, acc.x));
    acc.y = fmaf(ax, by, fmaf( ay, bx, acc.y));
}

// ---------------------------------------------------------------------------
// D table in MFMA B-fragment order. Record (kc,t,p): 64 lanes x 8 bf16 (16B):
//   lane holds D[k = kc*32 + (lane>>4)*8 + j][n = t*16 + (lane&15)], j=0..7
// planes p: 0=Dr_hi 1=Dr_lo 2=Di_hi 3=Di_lo 4=(-Di)_hi 5=(-Di)_lo  (ifft dir)
// (fused kernel now reads only planes 0..3; negation done on the other operand)
// ---------------------------------------------------------------------------
__global__ void init_dtab(unsigned short* __restrict__ Dtab) {
    int idx = blockIdx.x * 256 + threadIdx.x;   // 36 recs * 64 lanes = 2304
    if (idx >= 2304) return;
    int rec = idx >> 6, lane = idx & 63;
    int p = rec % 6, t = (rec / 6) % 3, kc = rec / 18;
    unsigned short out[8];
    for (int j = 0; j < 8; ++j) {
        int k = kc * 32 + (lane >> 4) * 8 + j;
        int n = t * 16 + (lane & 15);
        float val = 0.0f;
        if (k < 40 && n < 40) {
            float ang = 6.28318530717958647692f * (float)((k * n) % 40) / 40.0f;
            float dr, di, s, c;
            sincosf(ang, &s, &c);
            dr = c; di = s;
            float base = (p < 2) ? dr : (p < 4) ? di : -di;
            __bf16 hi = (__bf16)base;
            if ((p & 1) == 0) val = (float)hi;
            else              val = (float)(__bf16)(base - (float)hi);
        }
        out[j] = __builtin_bit_cast(unsigned short, (__bf16)val);
    }
    unsigned short* dst = Dtab + (size_t)rec * 512 + lane * 8;
    for (int j = 0; j < 8; ++j) dst[j] = out[j];
}

// ---------------------------------------------------------------------------
// Small-edge fp32 kernel (head/tail only) — unchanged.
// ---------------------------------------------------------------------------
template<bool REAL_IN, bool RELU, bool REAL_OUT>
__global__ __launch_bounds__(256) void fft2_kernel(const void* __restrict__ inv,
                                                   void* __restrict__ outv,
                                                   int dir)
{
    const int img = blockIdx.x;
    const int tid = threadIdx.x;
    __shared__ float2 A[NPIX];
    __shared__ float2 T[NPIX];
    __shared__ float2 D[NPIX];
    __shared__ float2 tw[NIMG];

    if (tid < NIMG) {
        float ang = (float)dir * 6.28318530717958647692f * (float)tid / 40.0f;
        float s, c;
        sincosf(ang, &s, &c);
        tw[tid] = make_float2(c, s);
    }
    if (REAL_IN) {
        const float* in = (const float*)inv + (size_t)img * NPIX;
        for (int idx = tid; idx < NPIX; idx += 256)
            A[idx] = make_float2(in[idx], 0.0f);
    } else {
        const float2* in = (const float2*)inv + (size_t)img * NPIX;
        for (int idx = tid; idx < NPIX; idx += 256)
            A[idx] = in[idx];
    }
    __syncthreads();
    for (int idx = tid; idx < NPIX; idx += 256) {
        int a = idx / NIMG, b = idx - a * NIMG;
        D[idx] = tw[(a * b) % NIMG];
    }
    __syncthreads();

    for (int idx = tid; idx < NPIX; idx += 256) {
        int h = idx / NIMG, v = idx - h * NIMG;
        float2 s = make_float2(0.0f, 0.0f);
        const float2* Arow = &A[h * NIMG];
        #pragma unroll
        for (int w = 0; w < NIMG; ++w) {
            float2 a = Arow[w];
            float2 d = D[w * NIMG + v];
            s.x += a.x * d.x - a.y * d.y;
            s.y += a.x * d.y + a.y * d.x;
        }
        T[idx] = s;
    }
    __syncthreads();

    for (int idx = tid; idx < NPIX; idx += 256) {
        int u = idx / NIMG, v = idx - u * NIMG;
        float2 s = make_float2(0.0f, 0.0f);
        const float2* Du = &D[u * NIMG];
        #pragma unroll
        for (int h = 0; h < NIMG; ++h) {
            float2 t = T[h * NIMG + v];
            float2 d = Du[h];
            s.x += t.x * d.x - t.y * d.y;
            s.y += t.x * d.y + t.y * d.x;
        }
        s.x *= 0.025f;
        s.y *= 0.025f;
        if (RELU) { s.x = fmaxf(s.x, 0.0f); s.y = fmaxf(s.y, 0.0f); }
        if (REAL_OUT) {
            ((float*)outv)[(size_t)img * NPIX + idx] = s.x;
        } else {
            ((float2*)outv)[(size_t)img * NPIX + idx] = s;
        }
    }
}

// Unified 12-MFMA complex tile update (row pass: A=x, B=D):
//   aR += xr*dr + p*di ; aI += q*di + xi*dr
// where (p,q) = rep0: (-xi, xr) ; rep1: (xi, -xr).
__device__ __forceinline__ void mac_cplx(f32x4& aR, f32x4& aI,
    bf16x8 xrh, bf16x8 xrl, bf16x8 xih, bf16x8 xil,
    bf16x8 ph,  bf16x8 pl,  bf16x8 qh,  bf16x8 ql,
    bf16x8 drh, bf16x8 drl, bf16x8 dih, bf16x8 dil)
{
    aR = MFMA(xrh, drh, aR, 0, 0, 0);
    aR = MFMA(xrl, drh, aR, 0, 0, 0);
    aR = MFMA(xrh, drl, aR, 0, 0, 0);
    aR = MFMA(ph,  dih, aR, 0, 0, 0);
    aR = MFMA(pl,  dih, aR, 0, 0, 0);
    aR = MFMA(ph,  dil, aR, 0, 0, 0);
    aI = MFMA(qh,  dih, aI, 0, 0, 0);
    aI = MFMA(ql,  dih, aI, 0, 0, 0);
    aI = MFMA(qh,  dil, aI, 0, 0, 0);
    aI = MFMA(xih, drh, aI, 0, 0, 0);
    aI = MFMA(xil, drh, aI, 0, 0, 0);
    aI = MFMA(xih, drl, aI, 0, 0, 0);
}

// Col pass (A=D, B=T): aR += dr*tr + di*p ; aI += di*q + dr*ti
// where (p,q) = rep0: (-ti, tr) ; rep1: (ti, -tr).
__device__ __forceinline__ void mac_cplx_col(f32x4& aR, f32x4& aI,
    bf16x8 drh, bf16x8 drl, bf16x8 dih, bf16x8 dil,
    bf16x8 trh, bf16x8 trl, bf16x8 tih, bf16x8 til,
    bf16x8 ph,  bf16x8 pl,  bf16x8 qh,  bf16x8 ql)
{
    aR = MFMA(drh, trh, aR, 0, 0, 0);
    aR = MFMA(drl, trh, aR, 0, 0, 0);
    aR = MFMA(drh, trl, aR, 0, 0, 0);
    aR = MFMA(dih, ph,  aR, 0, 0, 0);
    aR = MFMA(dil, ph,  aR, 0, 0, 0);
    aR = MFMA(dih, pl,  aR, 0, 0, 0);
    aI = MFMA(dih, qh,  aI, 0, 0, 0);
    aI = MFMA(dil, qh,  aI, 0, 0, 0);
    aI = MFMA(dih, ql,  aI, 0, 0, 0);
    aI = MFMA(drh, tih, aI, 0, 0, 0);
    aI = MFMA(drl, tih, aI, 0, 0, 0);
    aI = MFMA(drh, til, aI, 0, 0, 0);
}

// Mix tile update: C += F*W (complex). Negation on the A-side (-Fi planes),
// so the W fragment set needs only 4 planes.
__device__ __forceinline__ void mac_mix(f32x4& aR, f32x4& aI,
    bf16x8 frh, bf16x8 frl, bf16x8 fih, bf16x8 fil, bf16x8 fnih, bf16x8 fnil,
    bf16x8 wrh, bf16x8 wrl, bf16x8 wih, bf16x8 wil)
{
    aR = MFMA(frh,  wrh, aR, 0, 0, 0);
    aR = MFMA(frl,  wrh, aR, 0, 0, 0);
    aR = MFMA(frh,  wrl, aR, 0, 0, 0);
    aR = MFMA(fnih, wih, aR, 0, 0, 0);
    aR = MFMA(fnil, wih, aR, 0, 0, 0);
    aR = MFMA(fnih, wil, aR, 0, 0, 0);
    aI = MFMA(frh,  wih, aI, 0, 0, 0);
    aI = MFMA(frl,  wih, aI, 0, 0, 0);
    aI = MFMA(frh,  wil, aI, 0, 0, 0);
    aI = MFMA(fih,  wrh, aI, 0, 0, 0);
    aI = MFMA(fil,  wrh, aI, 0, 0, 0);
    aI = MFMA(fih,  wrl, aI, 0, 0, 0);
}

// ---------------------------------------------------------------------------
// MFMA channel mix — unchanged (passing, ~72 us).
// ---------------------------------------------------------------------------
__global__ __launch_bounds__(512, 2) void mix_mfma_kernel(const float2* __restrict__ F,
                                                          const float2* __restrict__ W,
                                                          float2* __restrict__ M)
{
    __shared__ alignas(16) char smem[102912];
    float2* raw  = (float2*)smem;               // 16*RST complex = 41216 B
    float2* outt = (float2*)(smem + 41216);     // 16*OST complex = 61696 B
    float2* lw   = (float2*)smem;               // W stage overlay: 1600*8 = 102400 B

    const int tid  = threadIdx.x;
    const int w    = tid >> 6;
    const int lane = tid & 63;
    const int q    = lane >> 4;
    const int m    = lane & 15;
    const int fw   = blockIdx.x >> 3;
    const int bg   = blockIdx.x & 7;
    const int f0   = fw * 8;
    const int fsub = w;

    // ---- issue F stage loads for btile 0 early (latency hides under W staging)
    f32x4 pf[5];
    #pragma unroll
    for (int k = 0; k < 5; ++k) {
        int c = tid + (k << 9);
        int r = c >> 2, sub = c & 3;
        int b = r / 40, i = r - b * 40;
        const f32x4* g = (const f32x4*)(F + ((size_t)((bg * 32 + b) * 40 + i) * NPIX + f0));
        pf[k] = __builtin_nontemporal_load(g + sub);
    }

    // ---- stage W[:, :, f0..f0+7] into LDS: 1600 rows x 64 B, coalesced
    #pragma unroll
    for (int k = 0; k < 13; ++k) {
        int c = tid + (k << 9);              // 13*512 = 6656 >= 6400
        if (c < 6400) {
            int r = c >> 2, sub = c & 3;
            const f32x4* g = (const f32x4*)(W + ((size_t)r * NPIX + f0));
            *(f32x4*)&lw[r * 8 + sub * 2] = g[sub];
        }
    }
    __syncthreads();

    // ---- convert this wave's W fragments into registers (96 VGPR)
    bf16x8 wt[2][3][4];
    #pragma unroll
    for (int kc = 0; kc < 2; ++kc) {
        #pragma unroll
        for (int nt = 0; nt < 3; ++nt) {
            bf16x8 wrh = (bf16x8){}, wrl = (bf16x8){};
            bf16x8 wih = (bf16x8){}, wil = (bf16x8){};
            const int o = nt * 16 + m;
            const bool have = ((kc == 0) || (q == 0)) && (o < 40);
            if (have) {
                #pragma unroll
                for (int j = 0; j < 8; ++j) {
                    int i = kc * 32 + q * 8 + j;     // i < 40 guaranteed when have
                    float2 v = lw[(i * 40 + o) * 8 + fsub];
                    __bf16 h1 = (__bf16)v.x;
                    wrh[j] = h1; wrl[j] = (__bf16)(v.x - (float)h1);
                    __bf16 h2 = (__bf16)v.y;
                    wih[j] = h2; wil[j] = (__bf16)(v.y - (float)h2);
                }
            }
            wt[kc][nt][0] = wrh; wt[kc][nt][1] = wrl;
            wt[kc][nt][2] = wih; wt[kc][nt][3] = wil;
        }
    }
    __syncthreads();   // all lw reads done; LDS now reused as raw/outt

    #pragma unroll
    for (int bt = 0; bt < 2; ++bt) {
        const int btile = bg * 2 + bt;

        // ---- write staged regs -> raw slab
        #pragma unroll
        for (int k = 0; k < 5; ++k) {
            int c = tid + (k << 9);
            int r = c >> 2, sub = c & 3;
            int b = r / 40, i = r - b * 40;
            *(f32x4*)&raw[b * RST + i * 8 + sub * 2] = pf[k];
        }
        __syncthreads();

        // ---- prefetch next slab during compute
        if (bt == 0) {
            #pragma unroll
            for (int k = 0; k < 5; ++k) {
                int c = tid + (k << 9);
                int r = c >> 2, sub = c & 3;
                int b = r / 40, i = r - b * 40;
                const f32x4* g = (const f32x4*)(F + ((size_t)(((bg * 2 + 1) * 16 + b) * 40 + i) * NPIX + f0));
                pf[k] = __builtin_nontemporal_load(g + sub);
            }
        }

        f32x4 accR[3], accI[3];
        #pragma unroll
        for (int nt = 0; nt < 3; ++nt) {
            accR[nt] = (f32x4){0.f, 0.f, 0.f, 0.f};
            accI[nt] = (f32x4){0.f, 0.f, 0.f, 0.f};
        }

        #pragma unroll
        for (int kc = 0; kc < 2; ++kc) {
            const bool have = (kc == 0) || (q == 0);
            float re[8], im[8];
            #pragma unroll
            for (int j = 0; j < 8; ++j) {
                int i = kc * 32 + q * 8 + j;
                if (have) {
                    float2 v = raw[m * RST + i * 8 + fsub];
                    re[j] = v.x; im[j] = v.y;
                } else { re[j] = 0.f; im[j] = 0.f; }
            }
            bf16x8 frh, frl, fih, fil, fnih, fnil;
            #pragma unroll
            for (int j = 0; j < 8; ++j) {
                __bf16 h1 = (__bf16)re[j];
                frh[j] = h1;
                float lo = re[j] - (float)h1;
                frl[j] = (__bf16)lo;
                __bf16 h2 = (__bf16)im[j];
                fih[j] = h2;
                float lo2 = im[j] - (float)h2;
                fil[j] = (__bf16)lo2;
                fnih[j] = (__bf16)(-(float)h2);
                fnil[j] = (__bf16)(-lo2);
            }
            #pragma unroll
            for (int nt = 0; nt < 3; ++nt)
                mac_mix(accR[nt], accI[nt], frh, frl, fih, fil, fnih, fnil,
                        wt[kc][nt][0], wt[kc][nt][1], wt[kc][nt][2], wt[kc][nt][3]);
        }

        // ---- acc -> out slab (C row = q*4+g, col o = nt*16+m)
        #pragma unroll
        for (int nt = 0; nt < 3; ++nt)
            #pragma unroll
            for (int g2 = 0; g2 < 4; ++g2)
                outt[(q * 4 + g2) * OST + (nt * 16 + m) * 10 + fsub] =
                    make_float2(accR[nt][g2], accI[nt][g2]);
        __syncthreads();

        // ---- coalesced store (o < 40 rows only)
        #pragma unroll
        for (int k = 0; k < 5; ++k) {
            int c = tid + (k << 9);
            int r = c >> 2, sub = c & 3;
            int b = r / 40, o = r - b * 40;
            f32x4 v = *(const f32x4*)&outt[b * OST + o * 10 + sub * 2];
            f32x4* g = (f32x4*)(M + ((size_t)((btile * 16 + b) * 40 + o) * NPIX + f0));
            __builtin_nontemporal_store(v, g + sub);
        }
    }
}

// ---------------------------------------------------------------------------
// Fused ifft2 -> CReLU -> fft2, v4: 4-plane dreg (96 VGPR) + operand-side
// negation; per-tile load->mac interleave; __launch_bounds__(64,3) for
// 3 waves/SIMD; grid 2560 x 4 images (10 blocks/CU, LDS-capped).
// ---------------------------------------------------------------------------
__global__ __launch_bounds__(64, 3) void fused_mfma_kernel(const float2* __restrict__ in,
                                                           float2* __restrict__ outg,
                                                           const unsigned short* __restrict__ Dtab)
{
    __shared__ unsigned short Pl[4 * PSZ];   // 15360 B

    const int lane = threadIdx.x;
    const int q = lane >> 4;
    const int m = lane & 15;

    // 24 records: (kc,t) x planes {r_hi, r_lo, i_hi, i_lo} = 96 VGPR
    bf16x8 dreg[24];
    #pragma unroll
    for (int t = 0; t < 6; ++t)
        #pragma unroll
        for (int p = 0; p < 4; ++p)
            dreg[t * 4 + p] = ((const bf16x8*)Dtab)[((size_t)t * 6 + p) * 64 + lane];

    #pragma unroll 1
    for (int ii = 0; ii < 4; ++ii) {
        const size_t img  = (size_t)blockIdx.x + (size_t)ii * 2560;
        const size_t base = img * NPIX;

        // ---- Stage: fp32 complex -> 4 split-bf16 planes [h][w], rows 40..47 zero
        {
            const float4* src = (const float4*)(in + base);
            #pragma unroll
            for (int c = 0; c < 13; ++c) {
                int p = c * 64 + lane;
                if (p < 800) {
                    float4 v = src[p];
                    int h = p / 20, w2 = (p - h * 20) * 2;
                    int o = h * SW + w2;
                    __bf16 rh0 = (__bf16)v.x, ih0 = (__bf16)v.y;
                    __bf16 rh1 = (__bf16)v.z, ih1 = (__bf16)v.w;
                    ushort2 s0, s1, s2, s3;
                    s0.x = bits16(rh0); s0.y = bits16(rh1);
                    s1.x = bits16((__bf16)(v.x - (float)rh0));
                    s1.y = bits16((__bf16)(v.z - (float)rh1));
                    s2.x = bits16(ih0); s2.y = bits16(ih1);
                    s3.x = bits16((__bf16)(v.y - (float)ih0));
                    s3.y = bits16((__bf16)(v.w - (float)ih1));
                    *(ushort2*)&Pl[0 * PSZ + o] = s0;
                    *(ushort2*)&Pl[1 * PSZ + o] = s1;
                    *(ushort2*)&Pl[2 * PSZ + o] = s2;
                    *(ushort2*)&Pl[3 * PSZ + o] = s3;
                }
            }
            // zero pad rows 40..47 of all 4 planes (320 ushort4 = 5/thread)
            #pragma unroll
            for (int c = 0; c < 5; ++c) {
                int idx = c * 64 + lane;
                int pl = idx / 80, rem = idx - pl * 80;
                int r = 40 + rem / 10, c4 = (rem - (rem / 10) * 10) * 4;
                *(ushort4*)&Pl[pl * PSZ + r * SW + c4] = make_ushort4(0, 0, 0, 0);
            }
        }
        __syncthreads();

        f32x4 accR[3][3], accI[3][3];

        #pragma unroll
        for (int rep = 0; rep < 2; ++rep) {

            // ================= Row pass: T = A * D =================
            #pragma unroll
            for (int a = 0; a < 3; ++a)
                #pragma unroll
                for (int b = 0; b < 3; ++b) {
                    accR[a][b] = (f32x4){0.f, 0.f, 0.f, 0.f};
                    accI[a][b] = (f32x4){0.f, 0.f, 0.f, 0.f};
                }

            #pragma unroll
            for (int kc = 0; kc < 2; ++kc) {
                const bool have = (kc == 0) || (q == 0);
                #pragma unroll
                for (int mt = 0; mt < 3; ++mt) {
                    bf16x8 xrh, xrl, xih, xil;
                    if (have) {
                        int o = (mt * 16 + m) * SW + kc * 32 + q * 8;
                        xrh = *(const bf16x8*)&Pl[0 * PSZ + o];
                        xrl = *(const bf16x8*)&Pl[1 * PSZ + o];
                        xih = *(const bf16x8*)&Pl[2 * PSZ + o];
                        xil = *(const bf16x8*)&Pl[3 * PSZ + o];
                    } else {
                        xrh = (bf16x8){}; xrl = (bf16x8){};
                        xih = (bf16x8){}; xil = (bf16x8){};
                    }
                    bf16x8 ph, pl2, qh, ql;
                    if (rep == 0) { ph = bneg(xih); pl2 = bneg(xil); qh = xrh; ql = xrl; }
                    else          { ph = xih;       pl2 = xil;       qh = bneg(xrh); ql = bneg(xrl); }
                    __builtin_amdgcn_s_setprio(1);
                    #pragma unroll
                    for (int nt = 0; nt < 3; ++nt) {
                        const int rb = (kc * 3 + nt) * 4;
                        mac_cplx(accR[mt][nt], accI[mt][nt],
                                 xrh, xrl, xih, xil, ph, pl2, qh, ql,
                                 dreg[rb + 0], dreg[rb + 1], dreg[rb + 2], dreg[rb + 3]);
                    }
                    __builtin_amdgcn_s_setprio(0);
                }
            }
            __syncthreads();

            // ---- T epilogue: split to 4 bf16 planes [v][h] (h<40 cols only)
            #pragma unroll
            for (int mt = 0; mt < 3; ++mt) {
                int hb = mt * 16 + q * 4;
                if (hb < 40) {
                    #pragma unroll
                    for (int nt = 0; nt < 3; ++nt) {
                        int v = nt * 16 + m;
                        f32x4 r = accR[mt][nt], i2 = accI[mt][nt];
                        ushort4 srh, srl, sih, sil;
                        unsigned short* prh = (unsigned short*)&srh;
                        unsigned short* prl = (unsigned short*)&srl;
                        unsigned short* pih = (unsigned short*)&sih;
                        unsigned short* pil = (unsigned short*)&sil;
                        #pragma unroll
                        for (int g = 0; g < 4; ++g) {
                            __bf16 h1 = (__bf16)r[g];
                            prh[g] = bits16(h1);
                            prl[g] = bits16((__bf16)(r[g] - (float)h1));
                            __bf16 h2 = (__bf16)i2[g];
                            pih[g] = bits16(h2);
                            pil[g] = bits16((__bf16)(i2[g] - (float)h2));
                        }
                        int o = v * SW + hb;
                        *(ushort4*)&Pl[0 * PSZ + o] = srh;
                        *(ushort4*)&Pl[1 * PSZ + o] = srl;
                        *(ushort4*)&Pl[2 * PSZ + o] = sih;
                        *(ushort4*)&Pl[3 * PSZ + o] = sil;
                    }
                }
            }
            __syncthreads();

            // ================= Col pass: C = D * T =================
            #pragma unroll
            for (int a = 0; a < 3; ++a)
                #pragma unroll
                for (int b = 0; b < 3; ++b) {
                    accR[a][b] = (f32x4){0.f, 0.f, 0.f, 0.f};
                    accI[a][b] = (f32x4){0.f, 0.f, 0.f, 0.f};
                }

            #pragma unroll
            for (int kc = 0; kc < 2; ++kc) {
                const bool have = (kc == 0) || (q == 0);
                #pragma unroll
                for (int nt = 0; nt < 3; ++nt) {
                    bf16x8 trh, trl, tih, til;
                    if (have) {
                        int o = (nt * 16 + m) * SW + kc * 32 + q * 8;
                        trh = *(const bf16x8*)&Pl[0 * PSZ + o];
                        trl = *(const bf16x8*)&Pl[1 * PSZ + o];
                        tih = *(const bf16x8*)&Pl[2 * PSZ + o];
                        til = *(const bf16x8*)&Pl[3 * PSZ + o];
                    } else {
                        trh = (bf16x8){}; trl = (bf16x8){};
                        tih = (bf16x8){}; til = (bf16x8){};
                    }
                    bf16x8 ph, pl2, qh, ql;
                    if (rep == 0) { ph = bneg(tih); pl2 = bneg(til); qh = trh; ql = trl; }
                    else          { ph = tih;       pl2 = til;       qh = bneg(trh); ql = bneg(trl); }
                    __builtin_amdgcn_s_setprio(1);
                    #pragma unroll
                    for (int mt = 0; mt < 3; ++mt) {
                        const int rb = (kc * 3 + mt) * 4;
                        mac_cplx_col(accR[mt][nt], accI[mt][nt],
                                     dreg[rb + 0], dreg[rb + 1], dreg[rb + 2], dreg[rb + 3],
                                     trh, trl, tih, til, ph, pl2, qh, ql);
                    }
                    __builtin_amdgcn_s_setprio(0);
                }
            }
            __syncthreads();

            // ---- Col epilogue
            if (rep == 0) {
                // scale + CReLU, write activation TRANSPOSED: At[v][u0..u0+3]
                #pragma unroll
                for (int mt = 0; mt < 3; ++mt) {
                    int u0 = mt * 16 + q * 4;
                    if (u0 < 40) {
                        #pragma unroll
                        for (int nt = 0; nt < 3; ++nt) {
                            int v = nt * 16 + m;
                            if (v < 40) {
                                f32x4 r = accR[mt][nt], i2 = accI[mt][nt];
                                ushort4 srh, srl, sih, sil;
                                unsigned short* prh = (unsigned short*)&srh;
                                unsigned short* prl = (unsigned short*)&srl;
                                unsigned short* pih = (unsigned short*)&sih;
                                unsigned short* pil = (unsigned short*)&sil;
                                #pragma unroll
                                for (int g = 0; g < 4; ++g) {
                                    float xr = fmaxf(r[g] * 0.025f, 0.f);
                                    float xi = fmaxf(i2[g] * 0.025f, 0.f);
                                    __bf16 h1 = (__bf16)xr;
                                    prh[g] = bits16(h1);
                                    prl[g] = bits16((__bf16)(xr - (float)h1));
                                    __bf16 h2 = (__bf16)xi;
                                    pih[g] = bits16(h2);
                                    pil[g] = bits16((__bf16)(xi - (float)h2));
                                }
                                int o = v * SW + u0;
                                *(ushort4*)&Pl[0 * PSZ + o] = srh;
                                *(ushort4*)&Pl[1 * PSZ + o] = srl;
                                *(ushort4*)&Pl[2 * PSZ + o] = sih;
                                *(ushort4*)&Pl[3 * PSZ + o] = sil;
                            }
                        }
                    }
                }
                __syncthreads();
            } else {
                // final: acc = Out^T -> store dst[v][u0..u0+3] contiguous
                float2* dst = outg + base;
                #pragma unroll
                for (int mt = 0; mt < 3; ++mt) {
                    int u0 = mt * 16 + q * 4;
                    if (u0 < 40) {
                        #pragma unroll
                        for (int nt = 0; nt < 3; ++nt) {
                            int v = nt * 16 + m;
                            if (v < 40) {
                                f32x4 r = accR[mt][nt], i2 = accI[mt][nt];
                                float4 s0, s1;
                                s0.x = r[0] * 0.025f; s0.y = i2[0] * 0.025f;
                                s0.z = r[1] * 0.025f; s0.w = i2[1] * 0.025f;
                                s1.x = r[2] * 0.025f; s1.y = i2[2] * 0.025f;
                                s1.z = r[3] * 0.025f; s1.w = i2[3] * 0.025f;
                                *(float4*)&dst[v * NIMG + u0]     = s0;
                                *(float4*)&dst[v * NIMG + u0 + 2] = s1;
                            }
                        }
                    }
                }
            }
        }
        __syncthreads();
    }
}

// ---------------------------------------------------------------------------
// Per-frequency channel mix (old VALU path — used for 1->40 head and 40->1 tail)
// ---------------------------------------------------------------------------
template<int INC, int OUTC, int BT, int OT>
__global__ __launch_bounds__(256) void mix_kernel(const float2* __restrict__ F,
                                                  const float2* __restrict__ W,
                                                  float2* __restrict__ M)
{
    const int tid = threadIdx.x;
    const int lane = tid & 63;
    const int wv = tid >> 6;
    const int f = (blockIdx.x % 25) * 64 + lane;
    const int bg = (blockIdx.x / 25) * 4 + wv;
    const int b0 = bg * BT;

    #pragma unroll
    for (int o0 = 0; o0 < OUTC; o0 += OT) {
        float2 acc[BT][OT];
        #pragma unroll
        for (int t = 0; t < BT; ++t)
            #pragma unroll
            for (int o = 0; o < OT; ++o)
                acc[t][o] = make_float2(0.0f, 0.0f);

        for (int i = 0; i < INC; ++i) {
            float2 fv[BT];
            #pragma unroll
            for (int t = 0; t < BT; ++t)
                fv[t] = F[((size_t)(b0 + t) * INC + i) * NPIX + f];
            float2 wr[OT];
            #pragma unroll
            for (int o = 0; o < OT; ++o)
                wr[o] = W[((size_t)i * OUTC + (o0 + o)) * NPIX + f];
            #pragma unroll
            for (int t = 0; t < BT; ++t)
                #pragma unroll
                for (int o = 0; o < OT; ++o)
                    cfma(acc[t][o], fv[t].x, fv[t].y, wr[o].x, wr[o].y);
        }
        #pragma unroll
        for (int t = 0; t < BT; ++t)
            #pragma unroll
            for (int o = 0; o < OT; ++o)
                M[((size_t)(b0 + t) * OUTC + (o0 + o)) * NPIX + f] = acc[t][o];
    }
}

extern "C" void kernel_launch(void* const* d_in, const int* in_sizes, int n_in,
                              void* d_out, int out_size, void* d_ws, size_t ws_size,
                              hipStream_t stream)
{
    const float* x = (const float*)d_in[0];
    const float2* w[6];
    for (int i = 0; i < 6; ++i) w[i] = (const float2*)d_in[1 + i];
    float* out = (float*)d_out;

    const size_t bufBytes = (size_t)256 * 40 * NPIX * sizeof(float2);  // 131.072 MB
    float2* A = (float2*)d_ws;
    float2* B = (float2*)((char*)d_ws + bufBytes);
    unsigned short* Dtab = (unsigned short*)((char*)d_ws + 2 * bufBytes);  // 36864 B

    const int FUSEGRID = 2560;                 // persistent: 4 images per wave
    const int MIXBLK = 25 * (256 / 4) / 4;     // 400

    init_dtab<<<9, 256, 0, stream>>>(Dtab);

    // L1 head: fft(x)
    fft2_kernel<true, false, false><<<256, 256, 0, stream>>>(x, A, -1);

    // L1 mix (K=1, old path) -> fused
    mix_kernel<1, 40, 4, 10><<<MIXBLK, 256, 0, stream>>>(A, w[0], B);
    fused_mfma_kernel<<<FUSEGRID, 64, 0, stream>>>(B, A, Dtab);

    // L2..L5: MFMA mix (in-kernel W staging) -> fused
    for (int l = 1; l <= 4; ++l) {
        mix_mfma_kernel<<<1600, 512, 0, stream>>>(A, w[l], B);
        fused_mfma_kernel<<<FUSEGRID, 64, 0, stream>>>(B, A, Dtab);
    }

    // L6: mix(40->1) then final ifft, real output
    mix_kernel<40, 1, 4, 1><<<MIXBLK, 256, 0, stream>>>(A, w[5], B);
    fft2_kernel<false, false, true><<<256, 256, 0, stream>>>(B, out, +1);
}

// Round 8
// 1343.098 us; speedup vs baseline: 1.5187x; 1.5187x over previous
//
#include <hip/hip_runtime.h>
#include <math.h>

#define NPIX 1600
#define NIMG 40
#define SW   40              // bf16 plane row stride: 80 B = 5*16 B -> conflict-free b128
#define PSZ  (48 * SW)       // shorts per plane (48 rows x 40 cols)

// mix_mfma LDS strides (complex units)
#define RST 322              // raw F slab: per-b stride = 40*8 + 2 pad (2576 B, 16-mult)
#define OST 482              // out slab: per-b stride = 48*10 + 2 pad (3856 B, 16-mult)

typedef __bf16 bf16x8 __attribute__((ext_vector_type(8)));
typedef float  f32x4  __attribute__((ext_vector_type(4)));
typedef unsigned int u32x4v __attribute__((ext_vector_type(4)));
#define MFMA __builtin_amdgcn_mfma_f32_16x16x32_bf16

__device__ __forceinline__ unsigned short bits16(__bf16 x) {
    return __builtin_bit_cast(unsigned short, x);
}

// exact bf16x8 negation (sign-bit flip on packed pairs)
__device__ __forceinline__ bf16x8 bneg(bf16x8 x) {
    u32x4v u = __builtin_bit_cast(u32x4v, x);
    u = u ^ (u32x4v){0x80008000u, 0x80008000u, 0x80008000u, 0x80008000u};
    return __builtin_bit_cast(bf16x8, u);
}

__device__ __forceinline__ void cfma(float2& acc, float ax, float ay, float bx, float by) {
    acc.x = fmaf(ax, bx, fmaf(-ay, by, acc.x));
    acc.y = fmaf(ax, by, fmaf( ay, bx, acc.y));
}

// ---------------------------------------------------------------------------
// D table in MFMA B-fragment order. Record (kc,t,p): 64 lanes x 8 bf16 (16B):
//   lane holds D[k = kc*32 + (lane>>4)*8 + j][n = t*16 + (lane&15)], j=0..7
// planes p: 0=Dr_hi 1=Dr_lo 2=Di_hi 3=Di_lo 4/5 unused by fused kernel now.
// ---------------------------------------------------------------------------
__global__ void init_dtab(unsigned short* __restrict__ Dtab) {
    int idx = blockIdx.x * 256 + threadIdx.x;   // 36 recs * 64 lanes = 2304
    if (idx >= 2304) return;
    int rec = idx >> 6, lane = idx & 63;
    int p = rec % 6, t = (rec / 6) % 3, kc = rec / 18;
    unsigned short out[8];
    for (int j = 0; j < 8; ++j) {
        int k = kc * 32 + (lane >> 4) * 8 + j;
        int n = t * 16 + (lane & 15);
        float val = 0.0f;
        if (k < 40 && n < 40) {
            float ang = 6.28318530717958647692f * (float)((k * n) % 40) / 40.0f;
            float dr, di, s, c;
            sincosf(ang, &s, &c);
            dr = c; di = s;
            float base = (p < 2) ? dr : (p < 4) ? di : -di;
            __bf16 hi = (__bf16)base;
            if ((p & 1) == 0) val = (float)hi;
            else              val = (float)(__bf16)(base - (float)hi);
        }
        out[j] = __builtin_bit_cast(unsigned short, (__bf16)val);
    }
    unsigned short* dst = Dtab + (size_t)rec * 512 + lane * 8;
    for (int j = 0; j < 8; ++j) dst[j] = out[j];
}

// ---------------------------------------------------------------------------
// Small-edge fp32 kernel (head/tail only) — unchanged.
// ---------------------------------------------------------------------------
template<bool REAL_IN, bool RELU, bool REAL_OUT>
__global__ __launch_bounds__(256) void fft2_kernel(const void* __restrict__ inv,
                                                   void* __restrict__ outv,
                                                   int dir)
{
    const int img = blockIdx.x;
    const int tid = threadIdx.x;
    __shared__ float2 A[NPIX];
    __shared__ float2 T[NPIX];
    __shared__ float2 D[NPIX];
    __shared__ float2 tw[NIMG];

    if (tid < NIMG) {
        float ang = (float)dir * 6.28318530717958647692f * (float)tid / 40.0f;
        float s, c;
        sincosf(ang, &s, &c);
        tw[tid] = make_float2(c, s);
    }
    if (REAL_IN) {
        const float* in = (const float*)inv + (size_t)img * NPIX;
        for (int idx = tid; idx < NPIX; idx += 256)
            A[idx] = make_float2(in[idx], 0.0f);
    } else {
        const float2* in = (const float2*)inv + (size_t)img * NPIX;
        for (int idx = tid; idx < NPIX; idx += 256)
            A[idx] = in[idx];
    }
    __syncthreads();
    for (int idx = tid; idx < NPIX; idx += 256) {
        int a = idx / NIMG, b = idx - a * NIMG;
        D[idx] = tw[(a * b) % NIMG];
    }
    __syncthreads();

    for (int idx = tid; idx < NPIX; idx += 256) {
        int h = idx / NIMG, v = idx - h * NIMG;
        float2 s = make_float2(0.0f, 0.0f);
        const float2* Arow = &A[h * NIMG];
        #pragma unroll
        for (int w = 0; w < NIMG; ++w) {
            float2 a = Arow[w];
            float2 d = D[w * NIMG + v];
            s.x += a.x * d.x - a.y * d.y;
            s.y += a.x * d.y + a.y * d.x;
        }
        T[idx] = s;
    }
    __syncthreads();

    for (int idx = tid; idx < NPIX; idx += 256) {
        int u = idx / NIMG, v = idx - u * NIMG;
        float2 s = make_float2(0.0f, 0.0f);
        const float2* Du = &D[u * NIMG];
        #pragma unroll
        for (int h = 0; h < NIMG; ++h) {
            float2 t = T[h * NIMG + v];
            float2 d = Du[h];
            s.x += t.x * d.x - t.y * d.y;
            s.y += t.x * d.y + t.y * d.x;
        }
        s.x *= 0.025f;
        s.y *= 0.025f;
        if (RELU) { s.x = fmaxf(s.x, 0.0f); s.y = fmaxf(s.y, 0.0f); }
        if (REAL_OUT) {
            ((float*)outv)[(size_t)img * NPIX + idx] = s.x;
        } else {
            ((float2*)outv)[(size_t)img * NPIX + idx] = s;
        }
    }
}

// Unified 12-MFMA complex tile update (row pass: A=x, B=D):
//   aR += xr*dr + p*di ; aI += q*di + xi*dr
// where (p,q) = rep0: (-xi, xr) ; rep1: (xi, -xr).  [HW-verified R7]
__device__ __forceinline__ void mac_cplx(f32x4& aR, f32x4& aI,
    bf16x8 xrh, bf16x8 xrl, bf16x8 xih, bf16x8 xil,
    bf16x8 ph,  bf16x8 pl,  bf16x8 qh,  bf16x8 ql,
    bf16x8 drh, bf16x8 drl, bf16x8 dih, bf16x8 dil)
{
    aR = MFMA(xrh, drh, aR, 0, 0, 0);
    aR = MFMA(xrl, drh, aR, 0, 0, 0);
    aR = MFMA(xrh, drl, aR, 0, 0, 0);
    aR = MFMA(ph,  dih, aR, 0, 0, 0);
    aR = MFMA(pl,  dih, aR, 0, 0, 0);
    aR = MFMA(ph,  dil, aR, 0, 0, 0);
    aI = MFMA(qh,  dih, aI, 0, 0, 0);
    aI = MFMA(ql,  dih, aI, 0, 0, 0);
    aI = MFMA(qh,  dil, aI, 0, 0, 0);
    aI = MFMA(xih, drh, aI, 0, 0, 0);
    aI = MFMA(xil, drh, aI, 0, 0, 0);
    aI = MFMA(xih, drl, aI, 0, 0, 0);
}

// Col pass (A=D, B=T): aR += dr*tr + di*p ; aI += di*q + dr*ti
// where (p,q) = rep0: (-ti, tr) ; rep1: (ti, -tr).  [HW-verified R7]
__device__ __forceinline__ void mac_cplx_col(f32x4& aR, f32x4& aI,
    bf16x8 drh, bf16x8 drl, bf16x8 dih, bf16x8 dil,
    bf16x8 trh, bf16x8 trl, bf16x8 tih, bf16x8 til,
    bf16x8 ph,  bf16x8 pl,  bf16x8 qh,  bf16x8 ql)
{
    aR = MFMA(drh, trh, aR, 0, 0, 0);
    aR = MFMA(drl, trh, aR, 0, 0, 0);
    aR = MFMA(drh, trl, aR, 0, 0, 0);
    aR = MFMA(dih, ph,  aR, 0, 0, 0);
    aR = MFMA(dil, ph,  aR, 0, 0, 0);
    aR = MFMA(dih, pl,  aR, 0, 0, 0);
    aI = MFMA(dih, qh,  aI, 0, 0, 0);
    aI = MFMA(dil, qh,  aI, 0, 0, 0);
    aI = MFMA(dih, ql,  aI, 0, 0, 0);
    aI = MFMA(drh, tih, aI, 0, 0, 0);
    aI = MFMA(drl, tih, aI, 0, 0, 0);
    aI = MFMA(drh, til, aI, 0, 0, 0);
}

// Mix tile update: C += F*W (complex). Negation on the A-side (-Fi planes),
// so the W fragment set needs only 4 planes.
__device__ __forceinline__ void mac_mix(f32x4& aR, f32x4& aI,
    bf16x8 frh, bf16x8 frl, bf16x8 fih, bf16x8 fil, bf16x8 fnih, bf16x8 fnil,
    bf16x8 wrh, bf16x8 wrl, bf16x8 wih, bf16x8 wil)
{
    aR = MFMA(frh,  wrh, aR, 0, 0, 0);
    aR = MFMA(frl,  wrh, aR, 0, 0, 0);
    aR = MFMA(frh,  wrl, aR, 0, 0, 0);
    aR = MFMA(fnih, wih, aR, 0, 0, 0);
    aR = MFMA(fnil, wih, aR, 0, 0, 0);
    aR = MFMA(fnih, wil, aR, 0, 0, 0);
    aI = MFMA(frh,  wih, aI, 0, 0, 0);
    aI = MFMA(frl,  wih, aI, 0, 0, 0);
    aI = MFMA(frh,  wil, aI, 0, 0, 0);
    aI = MFMA(fih,  wrh, aI, 0, 0, 0);
    aI = MFMA(fil,  wrh, aI, 0, 0, 0);
    aI = MFMA(fih,  wrl, aI, 0, 0, 0);
}

// ---------------------------------------------------------------------------
// MFMA channel mix — unchanged (passing, ~72 us).
// ---------------------------------------------------------------------------
__global__ __launch_bounds__(512, 2) void mix_mfma_kernel(const float2* __restrict__ F,
                                                          const float2* __restrict__ W,
                                                          float2* __restrict__ M)
{
    __shared__ alignas(16) char smem[102912];
    float2* raw  = (float2*)smem;               // 16*RST complex = 41216 B
    float2* outt = (float2*)(smem + 41216);     // 16*OST complex = 61696 B
    float2* lw   = (float2*)smem;               // W stage overlay: 1600*8 = 102400 B

    const int tid  = threadIdx.x;
    const int w    = tid >> 6;
    const int lane = tid & 63;
    const int q    = lane >> 4;
    const int m    = lane & 15;
    const int fw   = blockIdx.x >> 3;
    const int bg   = blockIdx.x & 7;
    const int f0   = fw * 8;
    const int fsub = w;

    // ---- issue F stage loads for btile 0 early (latency hides under W staging)
    f32x4 pf[5];
    #pragma unroll
    for (int k = 0; k < 5; ++k) {
        int c = tid + (k << 9);
        int r = c >> 2, sub = c & 3;
        int b = r / 40, i = r - b * 40;
        const f32x4* g = (const f32x4*)(F + ((size_t)((bg * 32 + b) * 40 + i) * NPIX + f0));
        pf[k] = __builtin_nontemporal_load(g + sub);
    }

    // ---- stage W[:, :, f0..f0+7] into LDS: 1600 rows x 64 B, coalesced
    #pragma unroll
    for (int k = 0; k < 13; ++k) {
        int c = tid + (k << 9);              // 13*512 = 6656 >= 6400
        if (c < 6400) {
            int r = c >> 2, sub = c & 3;
            const f32x4* g = (const f32x4*)(W + ((size_t)r * NPIX + f0));
            *(f32x4*)&lw[r * 8 + sub * 2] = g[sub];
        }
    }
    __syncthreads();

    // ---- convert this wave's W fragments into registers (96 VGPR)
    bf16x8 wt[2][3][4];
    #pragma unroll
    for (int kc = 0; kc < 2; ++kc) {
        #pragma unroll
        for (int nt = 0; nt < 3; ++nt) {
            bf16x8 wrh = (bf16x8){}, wrl = (bf16x8){};
            bf16x8 wih = (bf16x8){}, wil = (bf16x8){};
            const int o = nt * 16 + m;
            const bool have = ((kc == 0) || (q == 0)) && (o < 40);
            if (have) {
                #pragma unroll
                for (int j = 0; j < 8; ++j) {
                    int i = kc * 32 + q * 8 + j;     // i < 40 guaranteed when have
                    float2 v = lw[(i * 40 + o) * 8 + fsub];
                    __bf16 h1 = (__bf16)v.x;
                    wrh[j] = h1; wrl[j] = (__bf16)(v.x - (float)h1);
                    __bf16 h2 = (__bf16)v.y;
                    wih[j] = h2; wil[j] = (__bf16)(v.y - (float)h2);
                }
            }
            wt[kc][nt][0] = wrh; wt[kc][nt][1] = wrl;
            wt[kc][nt][2] = wih; wt[kc][nt][3] = wil;
        }
    }
    __syncthreads();   // all lw reads done; LDS now reused as raw/outt

    #pragma unroll
    for (int bt = 0; bt < 2; ++bt) {
        const int btile = bg * 2 + bt;

        // ---- write staged regs -> raw slab
        #pragma unroll
        for (int k = 0; k < 5; ++k) {
            int c = tid + (k << 9);
            int r = c >> 2, sub = c & 3;
            int b = r / 40, i = r - b * 40;
            *(f32x4*)&raw[b * RST + i * 8 + sub * 2] = pf[k];
        }
        __syncthreads();

        // ---- prefetch next slab during compute
        if (bt == 0) {
            #pragma unroll
            for (int k = 0; k < 5; ++k) {
                int c = tid + (k << 9);
                int r = c >> 2, sub = c & 3;
                int b = r / 40, i = r - b * 40;
                const f32x4* g = (const f32x4*)(F + ((size_t)(((bg * 2 + 1) * 16 + b) * 40 + i) * NPIX + f0));
                pf[k] = __builtin_nontemporal_load(g + sub);
            }
        }

        f32x4 accR[3], accI[3];
        #pragma unroll
        for (int nt = 0; nt < 3; ++nt) {
            accR[nt] = (f32x4){0.f, 0.f, 0.f, 0.f};
            accI[nt] = (f32x4){0.f, 0.f, 0.f, 0.f};
        }

        #pragma unroll
        for (int kc = 0; kc < 2; ++kc) {
            const bool have = (kc == 0) || (q == 0);
            float re[8], im[8];
            #pragma unroll
            for (int j = 0; j < 8; ++j) {
                int i = kc * 32 + q * 8 + j;
                if (have) {
                    float2 v = raw[m * RST + i * 8 + fsub];
                    re[j] = v.x; im[j] = v.y;
                } else { re[j] = 0.f; im[j] = 0.f; }
            }
            bf16x8 frh, frl, fih, fil, fnih, fnil;
            #pragma unroll
            for (int j = 0; j < 8; ++j) {
                __bf16 h1 = (__bf16)re[j];
                frh[j] = h1;
                float lo = re[j] - (float)h1;
                frl[j] = (__bf16)lo;
                __bf16 h2 = (__bf16)im[j];
                fih[j] = h2;
                float lo2 = im[j] - (float)h2;
                fil[j] = (__bf16)lo2;
                fnih[j] = (__bf16)(-(float)h2);
                fnil[j] = (__bf16)(-lo2);
            }
            #pragma unroll
            for (int nt = 0; nt < 3; ++nt)
                mac_mix(accR[nt], accI[nt], frh, frl, fih, fil, fnih, fnil,
                        wt[kc][nt][0], wt[kc][nt][1], wt[kc][nt][2], wt[kc][nt][3]);
        }

        // ---- acc -> out slab (C row = q*4+g, col o = nt*16+m)
        #pragma unroll
        for (int nt = 0; nt < 3; ++nt)
            #pragma unroll
            for (int g2 = 0; g2 < 4; ++g2)
                outt[(q * 4 + g2) * OST + (nt * 16 + m) * 10 + fsub] =
                    make_float2(accR[nt][g2], accI[nt][g2]);
        __syncthreads();

        // ---- coalesced store (o < 40 rows only)
        #pragma unroll
        for (int k = 0; k < 5; ++k) {
            int c = tid + (k << 9);
            int r = c >> 2, sub = c & 3;
            int b = r / 40, o = r - b * 40;
            f32x4 v = *(const f32x4*)&outt[b * OST + o * 10 + sub * 2];
            f32x4* g = (f32x4*)(M + ((size_t)((btile * 16 + b) * 40 + o) * NPIX + f0));
            __builtin_nontemporal_store(v, g + sub);
        }
    }
}

// ---------------------------------------------------------------------------
// Fused ifft2 -> CReLU -> fft2, v5: 3-wave blocks (192 thr) sharing image
// planes AND the D table in LDS. Wave wv owns row-tile mt=wv (row pass) and
// col-tile nt=wv (col pass): acc = 24 VGPR, no dreg -> VGPR ~100, <=128 cap.
// LDS = 15360 (planes) + 24576 (D) = 39936 B -> 4 blocks/CU = 12 waves/CU.
// Grid 1024 x 10 images. Transposed-rep1 + SW=40 + setprio retained.
// ---------------------------------------------------------------------------
__global__ __launch_bounds__(192, 4) void fused_mfma_kernel(const float2* __restrict__ in,
                                                            float2* __restrict__ outg,
                                                            const unsigned short* __restrict__ Dtab)
{
    __shared__ unsigned short Pl[4 * PSZ];     // 15360 B
    __shared__ unsigned short Dlds[24 * 512];  // 24576 B

    const int tid  = threadIdx.x;
    const int wv   = tid >> 6;
    const int lane = tid & 63;
    const int q    = lane >> 4;
    const int m    = lane & 15;

    // ---- load D table (24 recs: (kc*3+t)*4 + p, p in {r_hi,r_lo,i_hi,i_lo})
    #pragma unroll
    for (int c = 0; c < 8; ++c) {
        int idx = c * 192 + tid;              // 8*192 = 1536 = 24*64 exactly
        int rec = idx >> 6, l2 = idx & 63;
        int t = rec >> 2, p = rec & 3;
        *(f32x4*)&Dlds[rec * 512 + l2 * 8] =
            *(const f32x4*)(Dtab + ((size_t)(t * 6 + p) * 512 + l2 * 8));
    }

    #pragma unroll 1
    for (int ii = 0; ii < 10; ++ii) {
        const size_t img  = (size_t)blockIdx.x + (size_t)ii * 1024;
        const size_t base = img * NPIX;

        // ---- Stage: fp32 complex -> 4 split-bf16 planes [h][w], rows 40..47 zero
        {
            const float4* src = (const float4*)(in + base);
            #pragma unroll
            for (int c = 0; c < 5; ++c) {
                int p = c * 192 + tid;        // 5*192 = 960 >= 800
                if (p < 800) {
                    float4 v = src[p];
                    int h = p / 20, w2 = (p - h * 20) * 2;
                    int o = h * SW + w2;
                    __bf16 rh0 = (__bf16)v.x, ih0 = (__bf16)v.y;
                    __bf16 rh1 = (__bf16)v.z, ih1 = (__bf16)v.w;
                    ushort2 s0, s1, s2, s3;
                    s0.x = bits16(rh0); s0.y = bits16(rh1);
                    s1.x = bits16((__bf16)(v.x - (float)rh0));
                    s1.y = bits16((__bf16)(v.z - (float)rh1));
                    s2.x = bits16(ih0); s2.y = bits16(ih1);
                    s3.x = bits16((__bf16)(v.y - (float)ih0));
                    s3.y = bits16((__bf16)(v.w - (float)ih1));
                    *(ushort2*)&Pl[0 * PSZ + o] = s0;
                    *(ushort2*)&Pl[1 * PSZ + o] = s1;
                    *(ushort2*)&Pl[2 * PSZ + o] = s2;
                    *(ushort2*)&Pl[3 * PSZ + o] = s3;
                }
            }
            // zero pad rows 40..47 of all 4 planes (320 ushort4)
            #pragma unroll
            for (int c = 0; c < 2; ++c) {
                int idx = c * 192 + tid;      // 2*192 = 384 >= 320
                if (idx < 320) {
                    int pl = idx / 80, rem = idx - pl * 80;
                    int r = 40 + rem / 10, c4 = (rem - (rem / 10) * 10) * 4;
                    *(ushort4*)&Pl[pl * PSZ + r * SW + c4] = make_ushort4(0, 0, 0, 0);
                }
            }
        }
        __syncthreads();

        f32x4 accR[3], accI[3];

        #pragma unroll
        for (int rep = 0; rep < 2; ++rep) {

            // ================= Row pass: wave wv owns mt = wv =================
            #pragma unroll
            for (int a = 0; a < 3; ++a) {
                accR[a] = (f32x4){0.f, 0.f, 0.f, 0.f};
                accI[a] = (f32x4){0.f, 0.f, 0.f, 0.f};
            }

            #pragma unroll
            for (int kc = 0; kc < 2; ++kc) {
                const bool have = (kc == 0) || (q == 0);
                bf16x8 xrh, xrl, xih, xil;
                if (have) {
                    int o = (wv * 16 + m) * SW + kc * 32 + q * 8;
                    xrh = *(const bf16x8*)&Pl[0 * PSZ + o];
                    xrl = *(const bf16x8*)&Pl[1 * PSZ + o];
                    xih = *(const bf16x8*)&Pl[2 * PSZ + o];
                    xil = *(const bf16x8*)&Pl[3 * PSZ + o];
                } else {
                    xrh = (bf16x8){}; xrl = (bf16x8){};
                    xih = (bf16x8){}; xil = (bf16x8){};
                }
                bf16x8 ph, pl2, qh, ql;
                if (rep == 0) { ph = bneg(xih); pl2 = bneg(xil); qh = xrh; ql = xrl; }
                else          { ph = xih;       pl2 = xil;       qh = bneg(xrh); ql = bneg(xrl); }
                __builtin_amdgcn_s_setprio(1);
                #pragma unroll
                for (int nt = 0; nt < 3; ++nt) {
                    const int rb = (kc * 3 + nt) * 4;
                    bf16x8 d0 = *(const bf16x8*)&Dlds[(rb + 0) * 512 + lane * 8];
                    bf16x8 d1 = *(const bf16x8*)&Dlds[(rb + 1) * 512 + lane * 8];
                    bf16x8 d2 = *(const bf16x8*)&Dlds[(rb + 2) * 512 + lane * 8];
                    bf16x8 d3 = *(const bf16x8*)&Dlds[(rb + 3) * 512 + lane * 8];
                    mac_cplx(accR[nt], accI[nt],
                             xrh, xrl, xih, xil, ph, pl2, qh, ql,
                             d0, d1, d2, d3);
                }
                __builtin_amdgcn_s_setprio(0);
            }
            __syncthreads();

            // ---- T epilogue: wave wv writes its hb column block (hb < 40)
            {
                int hb = wv * 16 + q * 4;
                if (hb < 40) {
                    #pragma unroll
                    for (int nt = 0; nt < 3; ++nt) {
                        int v = nt * 16 + m;
                        f32x4 r = accR[nt], i2 = accI[nt];
                        ushort4 srh, srl, sih, sil;
                        unsigned short* prh = (unsigned short*)&srh;
                        unsigned short* prl = (unsigned short*)&srl;
                        unsigned short* pih = (unsigned short*)&sih;
                        unsigned short* pil = (unsigned short*)&sil;
                        #pragma unroll
                        for (int g = 0; g < 4; ++g) {
                            __bf16 h1 = (__bf16)r[g];
                            prh[g] = bits16(h1);
                            prl[g] = bits16((__bf16)(r[g] - (float)h1));
                            __bf16 h2 = (__bf16)i2[g];
                            pih[g] = bits16(h2);
                            pil[g] = bits16((__bf16)(i2[g] - (float)h2));
                        }
                        int o = v * SW + hb;
                        *(ushort4*)&Pl[0 * PSZ + o] = srh;
                        *(ushort4*)&Pl[1 * PSZ + o] = srl;
                        *(ushort4*)&Pl[2 * PSZ + o] = sih;
                        *(ushort4*)&Pl[3 * PSZ + o] = sil;
                    }
                }
            }
            __syncthreads();

            // ================= Col pass: wave wv owns nt = wv =================
            #pragma unroll
            for (int a = 0; a < 3; ++a) {
                accR[a] = (f32x4){0.f, 0.f, 0.f, 0.f};
                accI[a] = (f32x4){0.f, 0.f, 0.f, 0.f};
            }

            #pragma unroll
            for (int kc = 0; kc < 2; ++kc) {
                const bool have = (kc == 0) || (q == 0);
                bf16x8 trh, trl, tih, til;
                if (have) {
                    int o = (wv * 16 + m) * SW + kc * 32 + q * 8;
                    trh = *(const bf16x8*)&Pl[0 * PSZ + o];
                    trl = *(const bf16x8*)&Pl[1 * PSZ + o];
                    tih = *(const bf16x8*)&Pl[2 * PSZ + o];
                    til = *(const bf16x8*)&Pl[3 * PSZ + o];
                } else {
                    trh = (bf16x8){}; trl = (bf16x8){};
                    tih = (bf16x8){}; til = (bf16x8){};
                }
                bf16x8 ph, pl2, qh, ql;
                if (rep == 0) { ph = bneg(tih); pl2 = bneg(til); qh = trh; ql = trl; }
                else          { ph = tih;       pl2 = til;       qh = bneg(trh); ql = bneg(trl); }
                __builtin_amdgcn_s_setprio(1);
                #pragma unroll
                for (int mt = 0; mt < 3; ++mt) {
                    const int rb = (kc * 3 + mt) * 4;
                    bf16x8 d0 = *(const bf16x8*)&Dlds[(rb + 0) * 512 + lane * 8];
                    bf16x8 d1 = *(const bf16x8*)&Dlds[(rb + 1) * 512 + lane * 8];
                    bf16x8 d2 = *(const bf16x8*)&Dlds[(rb + 2) * 512 + lane * 8];
                    bf16x8 d3 = *(const bf16x8*)&Dlds[(rb + 3) * 512 + lane * 8];
                    mac_cplx_col(accR[mt], accI[mt],
                                 d0, d1, d2, d3,
                                 trh, trl, tih, til, ph, pl2, qh, ql);
                }
                __builtin_amdgcn_s_setprio(0);
            }
            __syncthreads();

            // ---- Col epilogue (wave wv owns nt = wv: v = wv*16+m)
            if (rep == 0) {
                // scale + CReLU, write activation TRANSPOSED: At[v][u0..u0+3]
                int v = wv * 16 + m;
                if (v < 40) {
                    #pragma unroll
                    for (int mt = 0; mt < 3; ++mt) {
                        int u0 = mt * 16 + q * 4;
                        if (u0 < 40) {
                            f32x4 r = accR[mt], i2 = accI[mt];
                            ushort4 srh, srl, sih, sil;
                            unsigned short* prh = (unsigned short*)&srh;
                            unsigned short* prl = (unsigned short*)&srl;
                            unsigned short* pih = (unsigned short*)&sih;
                            unsigned short* pil = (unsigned short*)&sil;
                            #pragma unroll
                            for (int g = 0; g < 4; ++g) {
                                float xr = fmaxf(r[g] * 0.025f, 0.f);
                                float xi = fmaxf(i2[g] * 0.025f, 0.f);
                                __bf16 h1 = (__bf16)xr;
                                prh[g] = bits16(h1);
                                prl[g] = bits16((__bf16)(xr - (float)h1));
                                __bf16 h2 = (__bf16)xi;
                                pih[g] = bits16(h2);
                                pil[g] = bits16((__bf16)(xi - (float)h2));
                            }
                            int o = v * SW + u0;
                            *(ushort4*)&Pl[0 * PSZ + o] = srh;
                            *(ushort4*)&Pl[1 * PSZ + o] = srl;
                            *(ushort4*)&Pl[2 * PSZ + o] = sih;
                            *(ushort4*)&Pl[3 * PSZ + o] = sil;
                        }
                    }
                }
                __syncthreads();
            } else {
                // final: acc = Out^T -> store dst[v][u0..u0+3] contiguous
                float2* dst = outg + base;
                int v = wv * 16 + m;
                if (v < 40) {
                    #pragma unroll
                    for (int mt = 0; mt < 3; ++mt) {
                        int u0 = mt * 16 + q * 4;
                        if (u0 < 40) {
                            f32x4 r = accR[mt], i2 = accI[mt];
                            float4 s0, s1;
                            s0.x = r[0] * 0.025f; s0.y = i2[0] * 0.025f;
                            s0.z = r[1] * 0.025f; s0.w = i2[1] * 0.025f;
                            s1.x = r[2] * 0.025f; s1.y = i2[2] * 0.025f;
                            s1.z = r[3] * 0.025f; s1.w = i2[3] * 0.025f;
                            *(float4*)&dst[v * NIMG + u0]     = s0;
                            *(float4*)&dst[v * NIMG + u0 + 2] = s1;
                        }
                    }
                }
            }
        }
        __syncthreads();   // planes reused next image
    }
}

// ---------------------------------------------------------------------------
// Per-frequency channel mix (old VALU path — used for 1->40 head and 40->1 tail)
// ---------------------------------------------------------------------------
template<int INC, int OUTC, int BT, int OT>
__global__ __launch_bounds__(256) void mix_kernel(const float2* __restrict__ F,
                                                  const float2* __restrict__ W,
                                                  float2* __restrict__ M)
{
    const int tid = threadIdx.x;
    const int lane = tid & 63;
    const int wv = tid >> 6;
    const int f = (blockIdx.x % 25) * 64 + lane;
    const int bg = (blockIdx.x / 25) * 4 + wv;
    const int b0 = bg * BT;

    #pragma unroll
    for (int o0 = 0; o0 < OUTC; o0 += OT) {
        float2 acc[BT][OT];
        #pragma unroll
        for (int t = 0; t < BT; ++t)
            #pragma unroll
            for (int o = 0; o < OT; ++o)
                acc[t][o] = make_float2(0.0f, 0.0f);

        for (int i = 0; i < INC; ++i) {
            float2 fv[BT];
            #pragma unroll
            for (int t = 0; t < BT; ++t)
                fv[t] = F[((size_t)(b0 + t) * INC + i) * NPIX + f];
            float2 wr[OT];
            #pragma unroll
            for (int o = 0; o < OT; ++o)
                wr[o] = W[((size_t)i * OUTC + (o0 + o)) * NPIX + f];
            #pragma unroll
            for (int t = 0; t < BT; ++t)
                #pragma unroll
                for (int o = 0; o < OT; ++o)
                    cfma(acc[t][o], fv[t].x, fv[t].y, wr[o].x, wr[o].y);
        }
        #pragma unroll
        for (int t = 0; t < BT; ++t)
            #pragma unroll
            for (int o = 0; o < OT; ++o)
                M[((size_t)(b0 + t) * OUTC + (o0 + o)) * NPIX + f] = acc[t][o];
    }
}

extern "C" void kernel_launch(void* const* d_in, const int* in_sizes, int n_in,
                              void* d_out, int out_size, void* d_ws, size_t ws_size,
                              hipStream_t stream)
{
    const float* x = (const float*)d_in[0];
    const float2* w[6];
    for (int i = 0; i < 6; ++i) w[i] = (const float2*)d_in[1 + i];
    float* out = (float*)d_out;

    const size_t bufBytes = (size_t)256 * 40 * NPIX * sizeof(float2);  // 131.072 MB
    float2* A = (float2*)d_ws;
    float2* B = (float2*)((char*)d_ws + bufBytes);
    unsigned short* Dtab = (unsigned short*)((char*)d_ws + 2 * bufBytes);  // 36864 B

    const int FUSEGRID = 1024;                 // 3-wave blocks, 10 images each
    const int MIXBLK = 25 * (256 / 4) / 4;     // 400

    init_dtab<<<9, 256, 0, stream>>>(Dtab);

    // L1 head: fft(x)
    fft2_kernel<true, false, false><<<256, 256, 0, stream>>>(x, A, -1);

    // L1 mix (K=1, old path) -> fused
    mix_kernel<1, 40, 4, 10><<<MIXBLK, 256, 0, stream>>>(A, w[0], B);
    fused_mfma_kernel<<<FUSEGRID, 192, 0, stream>>>(B, A, Dtab);

    // L2..L5: MFMA mix (in-kernel W staging) -> fused
    for (int l = 1; l <= 4; ++l) {
        mix_mfma_kernel<<<1600, 512, 0, stream>>>(A, w[l], B);
        fused_mfma_kernel<<<FUSEGRID, 192, 0, stream>>>(B, A, Dtab);
    }

    // L6: mix(40->1) then final ifft, real output
    mix_kernel<40, 1, 4, 1><<<MIXBLK, 256, 0, stream>>>(A, w[5], B);
    fft2_kernel<false, false, true><<<256, 256, 0, stream>>>(B, out, +1);
}